// Round 19
// baseline (189.428 us; speedup 1.0000x reference)
//
#include <hip/hip_runtime.h>

using short8  = __attribute__((ext_vector_type(8))) short;
using short4v = __attribute__((ext_vector_type(4))) short;
using f32x4   = __attribute__((ext_vector_type(4))) float;

#define HW   4800
#define MT   75
#define NPTS 1024
#define CDIM 256
#define NB   4
#define NROWS 4096
#define NG   60                          // g = b*15+ms, 5 m-tiles each

// ---- workspace layout (bytes) ----
#define OFF_BITS 0
#define SZ_BITS  (NROWS*MT*8)
#define OFF_PART (OFF_BITS + SZ_BITS)
#define SZ_PART  (NG*NPTS*16)
#define OFF_AG   (OFF_PART + SZ_PART)
#define SZ_AG    (NB*MT*16384*2)
#define OFF_KDNF (OFF_AG + SZ_AG)
#define SZ_KDNF  (NB*64*4096*2)
#define OFF_INVK (OFF_KDNF + SZ_KDNF)
#define SZ_INVK  (NROWS*4)
#define OFF_POS  (OFF_INVK + SZ_INVK)
#define SZ_POS   (NROWS*4)
#define OFF_NRM4 (OFF_POS + SZ_POS)
#define SZ_NRM4  (4*NB*HW*4)
#define OFF_ACC  (OFF_NRM4 + SZ_NRM4)
#define WS_TOTAL (OFF_ACC + 8)

__device__ inline unsigned short f2b(float v){
  unsigned int x; __builtin_memcpy(&x, &v, 4);
  x = x + 0x7fffu + ((x >> 16) & 1u);   // RNE
  return (unsigned short)(x >> 16);
}
__device__ inline int iclamp(int v, int lo, int hi){ return v < lo ? lo : (v > hi ? hi : v); }

__device__ inline void ins4(float v, float& a0, float& a1, float& a2, float& a3){
  if (v < a3){
    if (v < a2){ a3 = a2;
      if (v < a1){ a2 = a1;
        if (v < a0){ a1 = a0; a0 = v; } else a1 = v;
      } else a2 = v;
    } else a3 = v;
  }
}

__device__ inline void merge4(float& s0, float& s1, float& s2, float& s3, int off){
  float b0=__shfl_xor(s0,off), b1=__shfl_xor(s1,off), b2=__shfl_xor(s2,off), b3=__shfl_xor(s3,off);
  float c0=fminf(s0,b3), c1=fminf(s1,b2), c2=fminf(s2,b1), c3=fminf(s3,b0);
  float d0=fminf(c0,c2), e2=fmaxf(c0,c2), d1=fminf(c1,c3), e3=fmaxf(c1,c3);
  s0=fminf(d0,d1); s1=fmaxf(d0,d1); s2=fminf(e2,e3); s3=fmaxf(e2,e3);
}

__device__ inline void nearest4(float px, float py, int& o0, int& o1, int& o2, int& o3){
  float aa = px*px + py*py;
  int ic = iclamp((int)floorf(px*0.125f - 0.5f) - 1, 0, 76);
  int jc = iclamp((int)floorf(py*0.125f - 0.5f) - 1, 0, 56);
  float v0=1e30f,v1=1e30f,v2=1e30f,v3=1e30f;
  int   i0=0,i1=0,i2=0,i3=0;
  for (int jj=jc; jj<jc+4; ++jj){
    for (int ii=ic; ii<ic+4; ++ii){
      float cx = (ii+0.5f)*8.f, cy = (jj+0.5f)*8.f;
      float q = (aa + (cx*cx + cy*cy)) - 2.f*(px*cx + py*cy);
      int m = jj*80 + ii;
      if (q < v3){
        if (q < v2){ v3=v2; i3=i2;
          if (q < v1){ v2=v1; i2=i1;
            if (q < v0){ v1=v0; i1=i0; v0=q; i0=m; } else { v1=q; i1=m; }
          } else { v2=q; i2=m; }
        } else { v3=q; i3=m; }
      }
    }
  }
  o0=i0; o1=i1; o2=i2; o3=i3;
}

// Fused: blocks [0,1200) = d2t (f32x4 loads, short4v frag stores — R15-proven);
// blocks [1200,2224) = prep: kdnf pack + invk + POS (R9-proven bilinear, overlaps
// with d2t streaming blocks) + exclusion bits (fully written).
__global__ __launch_bounds__(256) void prep_d2t(
    const float* __restrict__ kp1, const float* __restrict__ wkp1,
    const float* __restrict__ kdesc, const float* __restrict__ desc2,
    const float* __restrict__ homo,
    unsigned short* __restrict__ kdnf, unsigned short* __restrict__ a_glob,
    float* __restrict__ nrm4, float* __restrict__ invk, float* __restrict__ pos,
    unsigned long long* __restrict__ bits, float* __restrict__ acc,
    unsigned int* __restrict__ cnt)
{
  int bx = blockIdx.x;
  if (bx < 1200){
    int mt = bx % 75;
    int rest = bx / 75;
    int cq = rest & 3, b = rest >> 2;
    int t = threadIdx.x;
    int mg = t & 15, cl = t >> 4;       // thread = (4 m, 4 channels)
    int m4 = mg*4;
    int c4 = cq*64 + cl*4;
    const float* src = desc2 + (size_t)b*CDIM*HW + (size_t)mt*64 + m4;
    f32x4 v0 = *(const f32x4*)(src + (size_t)(c4+0)*HW);
    f32x4 v1 = *(const f32x4*)(src + (size_t)(c4+1)*HW);
    f32x4 v2 = *(const f32x4*)(src + (size_t)(c4+2)*HW);
    f32x4 v3 = *(const f32x4*)(src + (size_t)(c4+3)*HW);
    __shared__ float red[16][64];
    #pragma unroll
    for (int i=0;i<4;++i)
      red[cl][m4+i] = v0[i]*v0[i]+v1[i]*v1[i]+v2[i]*v2[i]+v3[i]*v3[i];
    unsigned short* dst = a_glob + (size_t)(b*MT + mt)*16384;
    int kf = c4 >> 5, qd = (c4 >> 3) & 3, j0 = c4 & 7;
    #pragma unroll
    for (int i=0;i<4;++i){
      int m = m4 + i;
      int off16 = ((m>>4)*8 + kf)*64 + qd*16 + (m&15);
      short4v pk; pk[0]=(short)f2b(v0[i]); pk[1]=(short)f2b(v1[i]);
      pk[2]=(short)f2b(v2[i]); pk[3]=(short)f2b(v3[i]);
      __builtin_nontemporal_store(pk, (short4v*)(dst + off16*8 + j0));
    }
    __syncthreads();
    if (t < 64){
      float s = 0.f;
      #pragma unroll
      for (int o=0;o<16;++o) s += red[o][t];
      __builtin_nontemporal_store(s,
        nrm4 + (size_t)cq*(NB*HW) + (size_t)b*HW + mt*64 + t);
    }
    return;
  }

  int pb = bx - 1200;
  if (pb == 0 && threadIdx.x == 0){ acc[0] = 0.f; cnt[0] = 0u; }
  int wid  = pb*4 + (threadIdx.x >> 6);
  int lane = threadIdx.x & 63;
  int b = wid >> 10;
  const float* kr = kdesc + (size_t)wid*CDIM + lane*4;
  float k0=kr[0], k1=kr[1], k2=kr[2], k3=kr[3];
  float ss = k0*k0 + k1*k1 + k2*k2 + k3*k3;
  for (int off=32; off>0; off>>=1) ss += __shfl_xor(ss, off);
  float ivk = 1.0f/sqrtf(ss + 1e-8f);

  {
    int n = wid & 1023;
    int nt = n >> 4, nl2 = n & 15;
    int kf = lane >> 3, quad = (lane >> 1) & 3, j = (lane & 1)*4;
    short4v pk; pk[0]=(short)f2b(k0); pk[1]=(short)f2b(k1); pk[2]=(short)f2b(k2); pk[3]=(short)f2b(k3);
    __builtin_nontemporal_store(pk,
      (short4v*)(kdnf + ((size_t)(b*64 + nt) << 12) + ((kf*64 + quad*16 + nl2) << 3) + j));
  }

  // pos: bilinear sample at w_kp1/8 - 0.5 (R9-proven; overlaps d2t blocks)
  {
    float px = wkp1[(size_t)wid*2+0]*0.125f - 0.5f;
    float py = wkp1[(size_t)wid*2+1]*0.125f - 0.5f;
    float x0f = floorf(px), y0f = floorf(py);
    float wx = px - x0f, wy = py - y0f;
    int x0 = iclamp((int)x0f, 0, 79);
    int x1 = x0+1 > 79 ? 79 : x0+1;
    int y0 = iclamp((int)y0f, 0, 59);
    int y1 = y0+1 > 59 ? 59 : y0+1;
    const float* dp = desc2 + (size_t)b*CDIM*HW;
    float wss = 0.f, wdot = 0.f;
    int cbase = lane*4;
    #pragma unroll
    for (int j=0; j<4; ++j){
      const float* p = dp + (size_t)(cbase+j)*HW;
      float d00=p[y0*80+x0], d01=p[y0*80+x1];
      float d10=p[y1*80+x0], d11=p[y1*80+x1];
      float top = d00*(1.f-wx) + d01*wx;
      float bot = d10*(1.f-wx) + d11*wx;
      float wv  = top*(1.f-wy) + bot*wy;
      wss += wv*wv;
      float kvj = (j==0) ? k0 : (j==1) ? k1 : (j==2) ? k2 : k3;
      wdot += wv*kvj;
    }
    for (int off=32; off>0; off>>=1){ wss += __shfl_xor(wss, off); wdot += __shfl_xor(wdot, off); }
    if (lane == 0){
      invk[wid] = ivk;
      float invw = 1.0f/sqrtf(wss + 1e-8f);
      pos[wid] = 2.f - 2.f*(wdot*ivk*invw);
    }
  }

  float qx = kp1[(size_t)wid*2+0], qy = kp1[(size_t)wid*2+1];
  int c10,c11,c12,c13; nearest4(qx, qy, c10,c11,c12,c13);
  int myc = (lane==1) ? c11 : (lane==2) ? c12 : (lane==3) ? c13 : c10;
  float h0=homo[b*9+0], h1=homo[b*9+1], h2=homo[b*9+2];
  float h3=homo[b*9+3], h4=homo[b*9+4], h5=homo[b*9+5];
  float h6=homo[b*9+6], h7=homo[b*9+7], h8=homo[b*9+8];
  int d0=0,d1=0,d2=0,d3=0;
  if (lane < 4){
    int ii = myc % 80, jj = myc / 80;
    float cx = (ii+0.5f)*8.f, cy = (jj+0.5f)*8.f;
    float wz  = h6*cx + h7*cy + h8;
    float wxp = (h0*cx + h1*cy + h2) / (wz + 1e-8f);
    float wyp = (h3*cx + h4*cy + h5) / (wz + 1e-8f);
    nearest4(wxp, wyp, d0,d1,d2,d3);
  }
  unsigned long long w1 = 0ull, w2 = 0ull;
  int l64 = lane + 64;
  #pragma unroll
  for (int s=0; s<4; ++s){
    int e0=__shfl(d0,s), e1=__shfl(d1,s), e2=__shfl(d2,s), e3=__shfl(d3,s);
    #define ADDB(E) { if (((E)>>6)==lane) w1 |= 1ull<<((E)&63); \
                      if (((E)>>6)==l64)  w2 |= 1ull<<((E)&63); }
    ADDB(e0) ADDB(e1) ADDB(e2) ADDB(e3)
    #undef ADDB
  }
  unsigned long long* brow = bits + (size_t)wid*MT;
  brow[lane] = w1;
  if (lane < MT-64) brow[64+lane] = w2;
}

// GEMM+select — EXACT R11/R16 structure (75us best): 5-tile mt-loop, per-tile
// register prefetch incl. w64 BEFORE the barrier (no persistent bits regs).
__global__ __launch_bounds__(256) void gemm_select(
    const unsigned short* __restrict__ kdnf, const unsigned short* __restrict__ a_glob,
    const unsigned long long* __restrict__ bits, const float* __restrict__ invk,
    const float* __restrict__ nrm4, f32x4* __restrict__ part)
{
  int idx = blockIdx.x;
  int x = idx & 7, r = idx >> 3;
  int gp = r >> 4, nh = r & 15;
  int g = gp*8 + x;                    // XCD-pinned by g%8
  if (g >= NG) return;
  int b = g / 15, ms = g - b*15;
  int t = threadIdx.x;
  int wave = t >> 6, lane = t & 63;
  int quad = lane >> 4, nl = lane & 15;

  __shared__ __align__(16) unsigned short ashare[16384];
  __shared__ float snrm[64];
  __shared__ f32x4 outbuf[64];

  int n = nh*64 + wave*16 + nl;
  int row = b*NPTS + n;
  float ivk = invk[row];

  const unsigned short* kb = kdnf + ((size_t)(b*64 + nh*4 + wave) << 12);
  short8 bf0 = *(const short8*)(kb + ((0*64 + lane)<<3));
  short8 bf1 = *(const short8*)(kb + ((1*64 + lane)<<3));
  short8 bf2 = *(const short8*)(kb + ((2*64 + lane)<<3));
  short8 bf3 = *(const short8*)(kb + ((3*64 + lane)<<3));
  short8 bf4 = *(const short8*)(kb + ((4*64 + lane)<<3));
  short8 bf5 = *(const short8*)(kb + ((5*64 + lane)<<3));
  short8 bf6 = *(const short8*)(kb + ((6*64 + lane)<<3));
  short8 bf7 = *(const short8*)(kb + ((7*64 + lane)<<3));

  float s0=1e30f,s1=1e30f,s2=1e30f,s3=1e30f;

  #pragma unroll 1
  for (int j=0; j<5; ++j){
    int mt = ms*5 + j;
    int tile = b*MT + mt;
    // prefetch cluster: 8 a_glob loads + nrm4 + w64 all in flight together
    const unsigned short* ag = a_glob + (size_t)tile*16384;
    short8 t0 = *(const short8*)(ag + ((0*256 + t) << 3));
    short8 t1 = *(const short8*)(ag + ((1*256 + t) << 3));
    short8 t2 = *(const short8*)(ag + ((2*256 + t) << 3));
    short8 t3 = *(const short8*)(ag + ((3*256 + t) << 3));
    short8 t4 = *(const short8*)(ag + ((4*256 + t) << 3));
    short8 t5 = *(const short8*)(ag + ((5*256 + t) << 3));
    short8 t6 = *(const short8*)(ag + ((6*256 + t) << 3));
    short8 t7 = *(const short8*)(ag + ((7*256 + t) << 3));
    float nA=0.f,nB=0.f,nC=0.f,nD=0.f;
    if (t < 64){
      size_t o = (size_t)b*HW + (size_t)mt*64 + t;
      nA = nrm4[o];
      nB = nrm4[(size_t)NB*HW + o];
      nC = nrm4[2*(size_t)NB*HW + o];
      nD = nrm4[3*(size_t)NB*HW + o];
    }
    unsigned long long w64 = bits[(size_t)row*MT + mt];
    __syncthreads();   // prev tile's readers done; safe to overwrite LDS
    *(short8*)(ashare + ((0*256 + t) << 3)) = t0;
    *(short8*)(ashare + ((1*256 + t) << 3)) = t1;
    *(short8*)(ashare + ((2*256 + t) << 3)) = t2;
    *(short8*)(ashare + ((3*256 + t) << 3)) = t3;
    *(short8*)(ashare + ((4*256 + t) << 3)) = t4;
    *(short8*)(ashare + ((5*256 + t) << 3)) = t5;
    *(short8*)(ashare + ((6*256 + t) << 3)) = t6;
    *(short8*)(ashare + ((7*256 + t) << 3)) = t7;
    if (t < 64) snrm[t] = rsqrtf(nA+nB+nC+nD + 1e-8f);
    __syncthreads();

    #pragma unroll
    for (int msub=0; msub<4; ++msub){
      f32x4 accA = {0.f,0.f,0.f,0.f}, accB = {0.f,0.f,0.f,0.f};
      #define KSTEP(KF, ACC, BF) { \
        short8 a = *(short8*)(ashare + (((msub*8 + (KF))*64 + lane) << 3)); \
        ACC = __builtin_amdgcn_mfma_f32_16x16x32_bf16(a, BF, ACC, 0, 0, 0); }
      KSTEP(0,accA,bf0) KSTEP(1,accA,bf1) KSTEP(2,accA,bf2) KSTEP(3,accA,bf3)
      KSTEP(4,accB,bf4) KSTEP(5,accB,bf5) KSTEP(6,accB,bf6) KSTEP(7,accB,bf7)
      #undef KSTEP
      #pragma unroll
      for (int rr=0; rr<4; ++rr){
        int ml2 = msub*16 + quad*4 + rr;   // C/D: col=lane&15 (=n), row=quad*4+rr
        float val = 2.f - 2.f*(accA[rr]+accB[rr])*snrm[ml2]*ivk;
        if (!((w64 >> ml2) & 1ull)) ins4(val, s0,s1,s2,s3);
      }
    }
  }

  merge4(s0,s1,s2,s3,16);
  merge4(s0,s1,s2,s3,32);
  if (lane < 16) outbuf[wave*16 + nl] = (f32x4){s0,s1,s2,s3};
  __syncthreads();
  if (t < 64)
    __builtin_nontemporal_store(outbuf[t], part + ((size_t)g*NPTS + nh*64 + t));
}

// Pure merge+hinge: 256 blocks x 256 threads; wave = 4 rows; fully coalesced.
__global__ __launch_bounds__(256) void finalize(
    const f32x4* __restrict__ part, const float* __restrict__ pos,
    float* __restrict__ acc, unsigned int* __restrict__ cnt,
    float* __restrict__ out)
{
  int blk = blockIdx.x;
  int t = threadIdx.x;
  int wave = t >> 6, lane = t & 63;
  float hacc = 0.f;

  #pragma unroll
  for (int rr4 = 0; rr4 < 4; ++rr4){
    int row = blk*16 + wave*4 + rr4;
    int b = row >> 10, nn = row & 1023;
    float a0=1e30f, a1=1e30f, a2=1e30f, a3=1e30f;
    if (lane < 15){
      f32x4 v = part[(size_t)(b*15 + lane)*NPTS + nn];
      a0=v[0]; a1=v[1]; a2=v[2]; a3=v[3];
    }
    merge4(a0,a1,a2,a3,1);
    merge4(a0,a1,a2,a3,2);
    merge4(a0,a1,a2,a3,4);
    merge4(a0,a1,a2,a3,8);
    if (lane == 0){
      float p = pos[row];
      hacc += fmaxf(p-a0+1.f,0.f) + fmaxf(p-a1+1.f,0.f)
            + fmaxf(p-a2+1.f,0.f) + fmaxf(p-a3+1.f,0.f);
    }
  }

  __shared__ float ls[4];
  if (lane == 0) ls[wave] = hacc;
  __syncthreads();
  if (t == 0){
    atomicAdd(acc, ls[0]+ls[1]+ls[2]+ls[3]);
    __threadfence();
    unsigned int c = atomicAdd(cnt, 1u);
    if (c == 255u){
      float tot = atomicAdd(acc, 0.0f);
      out[0] = tot * (1.0f/16384.0f);
    }
  }
}

__global__ void ws_too_small(float* out){ out[0] = -12345.0f; }

extern "C" void kernel_launch(void* const* d_in, const int* in_sizes, int n_in,
                              void* d_out, int out_size, void* d_ws, size_t ws_size,
                              hipStream_t stream) {
  (void)in_sizes; (void)n_in; (void)out_size;
  if (ws_size < (size_t)WS_TOTAL){
    ws_too_small<<<1, 1, 0, stream>>>((float*)d_out);
    return;
  }
  const float* kp1   = (const float*)d_in[0];
  const float* wkp1  = (const float*)d_in[1];
  const float* kdesc = (const float*)d_in[2];
  const float* desc2 = (const float*)d_in[3];
  const float* homo  = (const float*)d_in[4];

  char* ws = (char*)d_ws;
  unsigned long long* bits = (unsigned long long*)(ws + OFF_BITS);
  f32x4*          part   = (f32x4*)(ws + OFF_PART);
  unsigned short* a_glob = (unsigned short*)(ws + OFF_AG);
  unsigned short* kdnf   = (unsigned short*)(ws + OFF_KDNF);
  float*          invk   = (float*)(ws + OFF_INVK);
  float*          pos    = (float*)(ws + OFF_POS);
  float*          nrm4   = (float*)(ws + OFF_NRM4);
  float*          acc    = (float*)(ws + OFF_ACC);
  unsigned int*   cnt    = (unsigned int*)(ws + OFF_ACC + 4);

  prep_d2t<<<2224, 256, 0, stream>>>(kp1, wkp1, kdesc, desc2, homo,
                                     kdnf, a_glob, nrm4, invk, pos, bits, acc, cnt);
  gemm_select<<<1024, 256, 0, stream>>>(kdnf, a_glob, bits, invk, nrm4, part);
  finalize<<<256, 256, 0, stream>>>(part, pos, acc, cnt, (float*)d_out);
}

// Round 20
// 171.006 us; speedup vs baseline: 1.1077x; 1.1077x over previous
//
#include <hip/hip_runtime.h>

using short8  = __attribute__((ext_vector_type(8))) short;
using short4v = __attribute__((ext_vector_type(4))) short;
using f32x4   = __attribute__((ext_vector_type(4))) float;

#define HW   4800
#define MT   75
#define NPTS 1024
#define CDIM 256
#define NB   4
#define NROWS 4096
#define NG   60                          // g = b*15+ms, 5 m-tiles each

// ---- workspace layout (bytes) ----
#define OFF_BITS 0
#define SZ_BITS  (NROWS*MT*8)
#define OFF_PART (OFF_BITS + SZ_BITS)
#define SZ_PART  (NG*NPTS*16)
#define OFF_AG   (OFF_PART + SZ_PART)
#define SZ_AG    (NB*MT*16384*2)
#define OFF_KDNF (OFF_AG + SZ_AG)
#define SZ_KDNF  (NB*64*4096*2)
#define OFF_INVK (OFF_KDNF + SZ_KDNF)
#define SZ_INVK  (NROWS*4)
#define OFF_NRM4 (OFF_INVK + SZ_INVK)
#define SZ_NRM4  (4*NB*HW*4)
#define OFF_ACC  (OFF_NRM4 + SZ_NRM4)
#define WS_TOTAL (OFF_ACC + 8)

__device__ inline unsigned short f2b(float v){
  unsigned int x; __builtin_memcpy(&x, &v, 4);
  x = x + 0x7fffu + ((x >> 16) & 1u);   // RNE
  return (unsigned short)(x >> 16);
}
__device__ inline float b2f(short s){
  unsigned int x = ((unsigned int)(unsigned short)s) << 16;
  float f; __builtin_memcpy(&f, &x, 4); return f;
}
__device__ inline int iclamp(int v, int lo, int hi){ return v < lo ? lo : (v > hi ? hi : v); }

__device__ inline void ins4(float v, float& a0, float& a1, float& a2, float& a3){
  if (v < a3){
    if (v < a2){ a3 = a2;
      if (v < a1){ a2 = a1;
        if (v < a0){ a1 = a0; a0 = v; } else a1 = v;
      } else a2 = v;
    } else a3 = v;
  }
}

__device__ inline void merge4(float& s0, float& s1, float& s2, float& s3, int off){
  float b0=__shfl_xor(s0,off), b1=__shfl_xor(s1,off), b2=__shfl_xor(s2,off), b3=__shfl_xor(s3,off);
  float c0=fminf(s0,b3), c1=fminf(s1,b2), c2=fminf(s2,b1), c3=fminf(s3,b0);
  float d0=fminf(c0,c2), e2=fmaxf(c0,c2), d1=fminf(c1,c3), e3=fmaxf(c1,c3);
  s0=fminf(d0,d1); s1=fmaxf(d0,d1); s2=fminf(e2,e3); s3=fmaxf(e2,e3);
}

__device__ inline void nearest4(float px, float py, int& o0, int& o1, int& o2, int& o3){
  float aa = px*px + py*py;
  int ic = iclamp((int)floorf(px*0.125f - 0.5f) - 1, 0, 76);
  int jc = iclamp((int)floorf(py*0.125f - 0.5f) - 1, 0, 56);
  float v0=1e30f,v1=1e30f,v2=1e30f,v3=1e30f;
  int   i0=0,i1=0,i2=0,i3=0;
  for (int jj=jc; jj<jc+4; ++jj){
    for (int ii=ic; ii<ic+4; ++ii){
      float cx = (ii+0.5f)*8.f, cy = (jj+0.5f)*8.f;
      float q = (aa + (cx*cx + cy*cy)) - 2.f*(px*cx + py*cy);
      int m = jj*80 + ii;
      if (q < v3){
        if (q < v2){ v3=v2; i3=i2;
          if (q < v1){ v2=v1; i2=i1;
            if (q < v0){ v1=v0; i1=i0; v0=q; i0=m; } else { v1=q; i1=m; }
          } else { v2=q; i2=m; }
        } else { v3=q; i3=m; }
      }
    }
  }
  o0=i0; o1=i1; o2=i2; o3=i3;
}

// Fused: blocks [0,1200) = d2t (f32x4 loads, short4v frag stores — R15-proven);
// blocks [1200,2224) = prep (kdnf pack + invk + exclusion bits, fully written).
__global__ __launch_bounds__(256) void prep_d2t(
    const float* __restrict__ kp1, const float* __restrict__ kdesc,
    const float* __restrict__ desc2, const float* __restrict__ homo,
    unsigned short* __restrict__ kdnf, unsigned short* __restrict__ a_glob,
    float* __restrict__ nrm4, float* __restrict__ invk,
    unsigned long long* __restrict__ bits, float* __restrict__ acc,
    unsigned int* __restrict__ cnt)
{
  int bx = blockIdx.x;
  if (bx < 1200){
    int mt = bx % 75;
    int rest = bx / 75;
    int cq = rest & 3, b = rest >> 2;
    int t = threadIdx.x;
    int mg = t & 15, cl = t >> 4;       // thread = (4 m, 4 channels)
    int m4 = mg*4;
    int c4 = cq*64 + cl*4;
    const float* src = desc2 + (size_t)b*CDIM*HW + (size_t)mt*64 + m4;
    f32x4 v0 = *(const f32x4*)(src + (size_t)(c4+0)*HW);
    f32x4 v1 = *(const f32x4*)(src + (size_t)(c4+1)*HW);
    f32x4 v2 = *(const f32x4*)(src + (size_t)(c4+2)*HW);
    f32x4 v3 = *(const f32x4*)(src + (size_t)(c4+3)*HW);
    __shared__ float red[16][64];
    #pragma unroll
    for (int i=0;i<4;++i)
      red[cl][m4+i] = v0[i]*v0[i]+v1[i]*v1[i]+v2[i]*v2[i]+v3[i]*v3[i];
    unsigned short* dst = a_glob + (size_t)(b*MT + mt)*16384;
    int kf = c4 >> 5, qd = (c4 >> 3) & 3, j0 = c4 & 7;
    #pragma unroll
    for (int i=0;i<4;++i){
      int m = m4 + i;
      int off16 = ((m>>4)*8 + kf)*64 + qd*16 + (m&15);
      short4v pk; pk[0]=(short)f2b(v0[i]); pk[1]=(short)f2b(v1[i]);
      pk[2]=(short)f2b(v2[i]); pk[3]=(short)f2b(v3[i]);
      __builtin_nontemporal_store(pk, (short4v*)(dst + off16*8 + j0));
    }
    __syncthreads();
    if (t < 64){
      float s = 0.f;
      #pragma unroll
      for (int o=0;o<16;++o) s += red[o][t];
      __builtin_nontemporal_store(s,
        nrm4 + (size_t)cq*(NB*HW) + (size_t)b*HW + mt*64 + t);
    }
    return;
  }

  int pb = bx - 1200;
  if (pb == 0 && threadIdx.x == 0){ acc[0] = 0.f; cnt[0] = 0u; }
  int wid  = pb*4 + (threadIdx.x >> 6);
  int lane = threadIdx.x & 63;
  int b = wid >> 10;
  const float* kr = kdesc + (size_t)wid*CDIM + lane*4;
  float k0=kr[0], k1=kr[1], k2=kr[2], k3=kr[3];
  float ss = k0*k0 + k1*k1 + k2*k2 + k3*k3;
  for (int off=32; off>0; off>>=1) ss += __shfl_xor(ss, off);
  if (lane == 0) invk[wid] = 1.0f/sqrtf(ss + 1e-8f);

  {
    int n = wid & 1023;
    int nt = n >> 4, nl2 = n & 15;
    int kf = lane >> 3, quad = (lane >> 1) & 3, j = (lane & 1)*4;
    short4v pk; pk[0]=(short)f2b(k0); pk[1]=(short)f2b(k1); pk[2]=(short)f2b(k2); pk[3]=(short)f2b(k3);
    __builtin_nontemporal_store(pk,
      (short4v*)(kdnf + ((size_t)(b*64 + nt) << 12) + ((kf*64 + quad*16 + nl2) << 3) + j));
  }

  float qx = kp1[(size_t)wid*2+0], qy = kp1[(size_t)wid*2+1];
  int c10,c11,c12,c13; nearest4(qx, qy, c10,c11,c12,c13);
  int myc = (lane==1) ? c11 : (lane==2) ? c12 : (lane==3) ? c13 : c10;
  float h0=homo[b*9+0], h1=homo[b*9+1], h2=homo[b*9+2];
  float h3=homo[b*9+3], h4=homo[b*9+4], h5=homo[b*9+5];
  float h6=homo[b*9+6], h7=homo[b*9+7], h8=homo[b*9+8];
  int d0=0,d1=0,d2=0,d3=0;
  if (lane < 4){
    int ii = myc % 80, jj = myc / 80;
    float cx = (ii+0.5f)*8.f, cy = (jj+0.5f)*8.f;
    float wz  = h6*cx + h7*cy + h8;
    float wxp = (h0*cx + h1*cy + h2) / (wz + 1e-8f);
    float wyp = (h3*cx + h4*cy + h5) / (wz + 1e-8f);
    nearest4(wxp, wyp, d0,d1,d2,d3);
  }
  unsigned long long w1 = 0ull, w2 = 0ull;
  int l64 = lane + 64;
  #pragma unroll
  for (int s=0; s<4; ++s){
    int e0=__shfl(d0,s), e1=__shfl(d1,s), e2=__shfl(d2,s), e3=__shfl(d3,s);
    #define ADDB(E) { if (((E)>>6)==lane) w1 |= 1ull<<((E)&63); \
                      if (((E)>>6)==l64)  w2 |= 1ull<<((E)&63); }
    ADDB(e0) ADDB(e1) ADDB(e2) ADDB(e3)
    #undef ADDB
  }
  unsigned long long* brow = bits + (size_t)wid*MT;
  brow[lane] = w1;
  if (lane < MT-64) brow[64+lane] = w2;
}

// GEMM+select — EXACT R11/R16 structure (75us best): 5-tile mt-loop, per-tile
// register prefetch incl. w64 BEFORE the barrier (no persistent bits regs).
__global__ __launch_bounds__(256) void gemm_select(
    const unsigned short* __restrict__ kdnf, const unsigned short* __restrict__ a_glob,
    const unsigned long long* __restrict__ bits, const float* __restrict__ invk,
    const float* __restrict__ nrm4, f32x4* __restrict__ part)
{
  int idx = blockIdx.x;
  int x = idx & 7, r = idx >> 3;
  int gp = r >> 4, nh = r & 15;
  int g = gp*8 + x;                    // XCD-pinned by g%8
  if (g >= NG) return;
  int b = g / 15, ms = g - b*15;
  int t = threadIdx.x;
  int wave = t >> 6, lane = t & 63;
  int quad = lane >> 4, nl = lane & 15;

  __shared__ __align__(16) unsigned short ashare[16384];
  __shared__ float snrm[64];
  __shared__ f32x4 outbuf[64];

  int n = nh*64 + wave*16 + nl;
  int row = b*NPTS + n;
  float ivk = invk[row];

  const unsigned short* kb = kdnf + ((size_t)(b*64 + nh*4 + wave) << 12);
  short8 bf0 = *(const short8*)(kb + ((0*64 + lane)<<3));
  short8 bf1 = *(const short8*)(kb + ((1*64 + lane)<<3));
  short8 bf2 = *(const short8*)(kb + ((2*64 + lane)<<3));
  short8 bf3 = *(const short8*)(kb + ((3*64 + lane)<<3));
  short8 bf4 = *(const short8*)(kb + ((4*64 + lane)<<3));
  short8 bf5 = *(const short8*)(kb + ((5*64 + lane)<<3));
  short8 bf6 = *(const short8*)(kb + ((6*64 + lane)<<3));
  short8 bf7 = *(const short8*)(kb + ((7*64 + lane)<<3));

  float s0=1e30f,s1=1e30f,s2=1e30f,s3=1e30f;

  #pragma unroll 1
  for (int j=0; j<5; ++j){
    int mt = ms*5 + j;
    int tile = b*MT + mt;
    // prefetch cluster: 8 a_glob loads + nrm4 + w64 all in flight together
    const unsigned short* ag = a_glob + (size_t)tile*16384;
    short8 t0 = *(const short8*)(ag + ((0*256 + t) << 3));
    short8 t1 = *(const short8*)(ag + ((1*256 + t) << 3));
    short8 t2 = *(const short8*)(ag + ((2*256 + t) << 3));
    short8 t3 = *(const short8*)(ag + ((3*256 + t) << 3));
    short8 t4 = *(const short8*)(ag + ((4*256 + t) << 3));
    short8 t5 = *(const short8*)(ag + ((5*256 + t) << 3));
    short8 t6 = *(const short8*)(ag + ((6*256 + t) << 3));
    short8 t7 = *(const short8*)(ag + ((7*256 + t) << 3));
    float nA=0.f,nB=0.f,nC=0.f,nD=0.f;
    if (t < 64){
      size_t o = (size_t)b*HW + (size_t)mt*64 + t;
      nA = nrm4[o];
      nB = nrm4[(size_t)NB*HW + o];
      nC = nrm4[2*(size_t)NB*HW + o];
      nD = nrm4[3*(size_t)NB*HW + o];
    }
    unsigned long long w64 = bits[(size_t)row*MT + mt];
    __syncthreads();   // prev tile's readers done; safe to overwrite LDS
    *(short8*)(ashare + ((0*256 + t) << 3)) = t0;
    *(short8*)(ashare + ((1*256 + t) << 3)) = t1;
    *(short8*)(ashare + ((2*256 + t) << 3)) = t2;
    *(short8*)(ashare + ((3*256 + t) << 3)) = t3;
    *(short8*)(ashare + ((4*256 + t) << 3)) = t4;
    *(short8*)(ashare + ((5*256 + t) << 3)) = t5;
    *(short8*)(ashare + ((6*256 + t) << 3)) = t6;
    *(short8*)(ashare + ((7*256 + t) << 3)) = t7;
    if (t < 64) snrm[t] = rsqrtf(nA+nB+nC+nD + 1e-8f);
    __syncthreads();

    #pragma unroll
    for (int msub=0; msub<4; ++msub){
      f32x4 accA = {0.f,0.f,0.f,0.f}, accB = {0.f,0.f,0.f,0.f};
      #define KSTEP(KF, ACC, BF) { \
        short8 a = *(short8*)(ashare + (((msub*8 + (KF))*64 + lane) << 3)); \
        ACC = __builtin_amdgcn_mfma_f32_16x16x32_bf16(a, BF, ACC, 0, 0, 0); }
      KSTEP(0,accA,bf0) KSTEP(1,accA,bf1) KSTEP(2,accA,bf2) KSTEP(3,accA,bf3)
      KSTEP(4,accB,bf4) KSTEP(5,accB,bf5) KSTEP(6,accB,bf6) KSTEP(7,accB,bf7)
      #undef KSTEP
      #pragma unroll
      for (int rr=0; rr<4; ++rr){
        int ml2 = msub*16 + quad*4 + rr;   // C/D: col=lane&15 (=n), row=quad*4+rr
        float val = 2.f - 2.f*(accA[rr]+accB[rr])*snrm[ml2]*ivk;
        if (!((w64 >> ml2) & 1ull)) ins4(val, s0,s1,s2,s3);
      }
    }
  }

  merge4(s0,s1,s2,s3,16);
  merge4(s0,s1,s2,s3,32);
  if (lane < 16) outbuf[wave*16 + nl] = (f32x4){s0,s1,s2,s3};
  __syncthreads();
  if (t < 64)
    __builtin_nontemporal_store(outbuf[t], part + ((size_t)g*NPTS + nh*64 + t));
}

// 256 blocks x 256 threads; block = 16 rows, wave = 4 rows (R12-proven).
__global__ __launch_bounds__(256) void finalize(
    const f32x4* __restrict__ part, const unsigned short* __restrict__ a_glob,
    const unsigned short* __restrict__ kdnf, const float* __restrict__ wkp1,
    const float* __restrict__ invk, float* __restrict__ acc,
    unsigned int* __restrict__ cnt, float* __restrict__ out)
{
  int blk = blockIdx.x;
  int t = threadIdx.x;
  int wave = t >> 6, lane = t & 63;
  int q = lane & 31, half = lane >> 5;
  int kf = q >> 2, qd = q & 3;
  float hacc = 0.f;

  #pragma unroll
  for (int rr4 = 0; rr4 < 4; ++rr4){
    int row = blk*16 + wave*4 + rr4;
    int b = row >> 10, nn = row & 1023;
    float px = wkp1[(size_t)row*2+0]*0.125f - 0.5f;
    float py = wkp1[(size_t)row*2+1]*0.125f - 0.5f;
    float x0f = floorf(px), y0f = floorf(py);
    float wx = px - x0f, wy = py - y0f;
    int x0 = iclamp((int)x0f, 0, 79);
    int x1 = x0+1 > 79 ? 79 : x0+1;
    int y0 = iclamp((int)y0f, 0, 59);
    int y1 = y0+1 > 59 ? 59 : y0+1;
    int mT = half ? (y0*80+x1) : (y0*80+x0);
    int mB = half ? (y1*80+x1) : (y1*80+x0);
    float wgt = half ? wx : (1.f - wx);
    int mlT = mT & 63, mlB = mB & 63;
    const short8 sT = *(const short8*)(a_glob + (size_t)(b*MT + (mT>>6))*16384 +
                        ((((mlT>>4)*8 + kf)*64 + qd*16 + (mlT&15)) << 3));
    const short8 sB = *(const short8*)(a_glob + (size_t)(b*MT + (mB>>6))*16384 +
                        ((((mlB>>4)*8 + kf)*64 + qd*16 + (mlB&15)) << 3));
    int nt = nn >> 4, nl2 = nn & 15;
    const short8 kv = *(const short8*)(kdnf + ((size_t)(b*64 + nt) << 12) +
                        ((kf*64 + qd*16 + nl2) << 3));
    float wss = 0.f, wdot = 0.f;
    #pragma unroll
    for (int j=0; j<8; ++j){
      float tj = b2f(sT[j]) * wgt;
      float bj = b2f(sB[j]) * wgt;
      tj += __shfl_xor(tj, 32);
      bj += __shfl_xor(bj, 32);
      float wv = tj*(1.f-wy) + bj*wy;
      wss  += wv*wv;
      wdot += wv*b2f(kv[j]);
    }
    #pragma unroll
    for (int off=1; off<32; off<<=1){
      wss  += __shfl_xor(wss, off);
      wdot += __shfl_xor(wdot, off);
    }
    float a0=1e30f, a1=1e30f, a2=1e30f, a3=1e30f;
    if (lane < 15){
      f32x4 v = part[(size_t)(b*15 + lane)*NPTS + nn];
      a0=v[0]; a1=v[1]; a2=v[2]; a3=v[3];
    }
    merge4(a0,a1,a2,a3,1);
    merge4(a0,a1,a2,a3,2);
    merge4(a0,a1,a2,a3,4);
    merge4(a0,a1,a2,a3,8);
    if (lane == 0){
      float invw = rsqrtf(wss + 1e-8f);
      float p = 2.f - 2.f*(wdot*invk[row]*invw);
      hacc += fmaxf(p-a0+1.f,0.f) + fmaxf(p-a1+1.f,0.f)
            + fmaxf(p-a2+1.f,0.f) + fmaxf(p-a3+1.f,0.f);
    }
  }

  __shared__ float ls[4];
  if (lane == 0) ls[wave] = hacc;
  __syncthreads();
  if (t == 0){
    atomicAdd(acc, ls[0]+ls[1]+ls[2]+ls[3]);
    __threadfence();
    unsigned int c = atomicAdd(cnt, 1u);
    if (c == 255u){
      float tot = atomicAdd(acc, 0.0f);
      out[0] = tot * (1.0f/16384.0f);
    }
  }
}

__global__ void ws_too_small(float* out){ out[0] = -12345.0f; }

extern "C" void kernel_launch(void* const* d_in, const int* in_sizes, int n_in,
                              void* d_out, int out_size, void* d_ws, size_t ws_size,
                              hipStream_t stream) {
  (void)in_sizes; (void)n_in; (void)out_size;
  if (ws_size < (size_t)WS_TOTAL){
    ws_too_small<<<1, 1, 0, stream>>>((float*)d_out);
    return;
  }
  const float* kp1   = (const float*)d_in[0];
  const float* wkp1  = (const float*)d_in[1];
  const float* kdesc = (const float*)d_in[2];
  const float* desc2 = (const float*)d_in[3];
  const float* homo  = (const float*)d_in[4];

  char* ws = (char*)d_ws;
  unsigned long long* bits = (unsigned long long*)(ws + OFF_BITS);
  f32x4*          part   = (f32x4*)(ws + OFF_PART);
  unsigned short* a_glob = (unsigned short*)(ws + OFF_AG);
  unsigned short* kdnf   = (unsigned short*)(ws + OFF_KDNF);
  float*          invk   = (float*)(ws + OFF_INVK);
  float*          nrm4   = (float*)(ws + OFF_NRM4);
  float*          acc    = (float*)(ws + OFF_ACC);
  unsigned int*   cnt    = (unsigned int*)(ws + OFF_ACC + 4);

  prep_d2t<<<2224, 256, 0, stream>>>(kp1, kdesc, desc2, homo,
                                     kdnf, a_glob, nrm4, invk, bits, acc, cnt);
  gemm_select<<<1024, 256, 0, stream>>>(kdnf, a_glob, bits, invk, nrm4, part);
  finalize<<<256, 256, 0, stream>>>(part, a_glob, kdnf, wkp1, invk, acc, cnt, (float*)d_out);
}